// Round 13
// baseline (456.327 us; speedup 1.0000x reference)
//
#include <hip/hip_runtime.h>
#include <stdint.h>

#define NEUR 1024
#define BM 128            // rows per block
#define THREADS 512
#define H1S 1040          // h1 half row stride bytes (512 bf16 + 16B pad)
#define L1S 80            // l1p row stride bytes

typedef short  s16x8  __attribute__((ext_vector_type(8)));
typedef __bf16 bf16x8 __attribute__((ext_vector_type(8)));
typedef float  f32x16 __attribute__((ext_vector_type(16)));

__device__ __forceinline__ unsigned short f2bf(float f){
  unsigned u = __builtin_bit_cast(unsigned, f);
  u += 0x7FFFu + ((u >> 16) & 1u);          // round-to-nearest-even
  return (unsigned short)(u >> 16);
}
__device__ __forceinline__ float bf2f(unsigned short h){
  unsigned u = ((unsigned)h) << 16;
  return __builtin_bit_cast(float, u);
}
__device__ __forceinline__ f32x16 mfma32(bf16x8 a, bf16x8 b, f32x16 c){
  return __builtin_amdgcn_mfma_f32_32x32x16_bf16(a, b, c, 0, 0, 0);
}
__device__ __forceinline__ f32x16 zero16(){
  f32x16 v;
#pragma unroll
  for (int r = 0; r < 16; ++r) v[r] = 0.f;
  return v;
}
__device__ __forceinline__ bf16x8 ld16(const void* p){
  return __builtin_bit_cast(bf16x8, *reinterpret_cast<const s16x8*>(p));
}

// Pre-swizzle weights into MFMA-fragment order (coalesced GEMM loads).
// w2opt[((nt*64 + ks)*64 + l)*8 + j] = bf16(W2[nt*32 + (l&31)][ks*16 + (l>>5)*8 + j])
// w1opt[((nt*2  + ks)*64 + l)*8 + j] = bf16(W1 padded to K=32, same fragment map)
__global__ void prep_kernel(const float* __restrict__ W1, const float* __restrict__ W2,
                            unsigned short* __restrict__ w2opt, unsigned short* __restrict__ w1opt){
  const int nchunks = NEUR * 128;
  const int total = nchunks + 4096;
  for (int i = blockIdx.x*blockDim.x + threadIdx.x; i < total; i += gridDim.x*blockDim.x){
    if (i < nchunks){
      const int col = i >> 7, c8 = i & 127;
      const float* src = W2 + (size_t)col*NEUR + c8*8;
      const int ks = c8 >> 1, lf = c8 & 1, lane = lf*32 + (col & 31), nt = col >> 5;
      unsigned short* dst = w2opt + (((size_t)(nt*64 + ks)*64 + lane) * 8);
#pragma unroll
      for (int j = 0; j < 8; ++j) dst[j] = f2bf(src[j]);
    } else {
      const int o = i - nchunks;
      const int nt = o >> 7, ks = (o >> 6) & 1, lane = o & 63;
      const int col = nt*32 + (lane & 31);
      unsigned short* dst = w1opt + (size_t)o * 8;
#pragma unroll
      for (int j = 0; j < 8; ++j){
        const int k = ks*16 + (lane >> 5)*8 + j;
        dst[j] = (k < 10) ? f2bf(W1[col*10 + k]) : (unsigned short)0;
      }
    }
  }
}

// finish: out = sigmoid(partial[0] + partial[1] + b3)
__global__ void finish_kernel(const float* __restrict__ pws, const float* __restrict__ b3,
                              float* __restrict__ out, int batch){
  const int total = batch * 3;
  for (int i = blockIdx.x*blockDim.x + threadIdx.x; i < total; i += gridDim.x*blockDim.x){
    const int j = i - (i/3)*3;
    const float v = pws[i] + pws[(size_t)total + i] + b3[j];
    out[i] = 1.f / (1.f + __expf(-v));
  }
}

// Main fused kernel: BM=128 x 512 cols per block; K split into 2 halves of 512.
// Wave tile = 128 rows x 64 cols: per K-step per wave 2 global B frags (TCP 50%)
// + 4 LDS A frags. GEMM2 = R8's MM4 distance-3 pipeline, operand-transposed.
__global__ __launch_bounds__(THREADS, 2) void mlp_kernel(
    const float* __restrict__ x,
    const float* __restrict__ Wx, const float* __restrict__ bxp,
    const float* __restrict__ Wu, const float* __restrict__ bup,
    const float* __restrict__ b1, const float* __restrict__ b2,
    const float* __restrict__ W3,
    const unsigned short* __restrict__ w2opt, const unsigned short* __restrict__ w1opt,
    float* __restrict__ pws, int batch)
{
  extern __shared__ char smem[];
  char* l1p = smem;                       // [128][L1S] 10240 B (dead after last GEMM1)
  char* h1  = smem + BM*L1S;              // [128][H1S] 133120 B  (total 143360)

  const int tid = threadIdx.x;
  const int l   = tid & 63;
  const int wid = tid >> 6;               // 8 waves; wave owns cols wid*64..+64, all 128 rows
  const int l31 = l & 31;
  const int lh  = l >> 5;
  const int bm  = blockIdx.x >> 1;
  const int bn  = blockIdx.x & 1;
  const long rbase = (long)bm * BM;

  // ---- 1. stage x tile (128*25 f32) into h1 region
  float* xs = (float*)h1;
  for (int i = tid; i < BM*25; i += THREADS) xs[i] = x[rbase*25 + i];
  __syncthreads();

  // ---- 2. l1 features (f32 exact), bf16-pad to K=32
  if (tid < BM){
    const float* xr = xs + tid*25;
    float l1v[10];
#pragma unroll
    for (int g = 0; g < 3; ++g)
#pragma unroll
      for (int o = 0; o < 2; ++o){
        float s = bxp[o];
#pragma unroll
        for (int i = 0; i < 5; ++i) s += xr[g + 3*i] * Wx[o*5 + i];
        l1v[g*2 + o] = fmaxf(s, 0.f);
      }
#pragma unroll
    for (int g = 0; g < 2; ++g)
#pragma unroll
      for (int o = 0; o < 2; ++o){
        float s = bup[o];
#pragma unroll
        for (int i = 0; i < 5; ++i) s += xr[15 + g + 2*i] * Wu[o*5 + i];
        l1v[6 + g*2 + o] = fmaxf(s, 0.f);
      }
    unsigned short* dst = (unsigned short*)(l1p + tid*L1S);
#pragma unroll
    for (int i = 0; i < 10; ++i) dst[i] = f2bf(l1v[i]);
#pragma unroll
    for (int i = 10; i < 32; ++i) dst[i] = 0;
  }
  __syncthreads();

  // ---- persistent GEMM2 accumulators: wave tile 128 rows x 64 cols
  f32x16 acc[4][2];                       // [row-tile mt][col-tile nt]
#pragma unroll
  for (int mt = 0; mt < 4; ++mt)
#pragma unroll
    for (int nt = 0; nt < 2; ++nt) acc[mt][nt] = zero16();

  // A fragment row bases in h1
  const int a0o = (0*32 + l31)*H1S + lh*16;
  const int a1o = (1*32 + l31)*H1S + lh*16;
  const int a2o = (2*32 + l31)*H1S + lh*16;
  const int a3o = (3*32 + l31)*H1S + lh*16;

  // wave's two B n-tiles; tile stride 65536 B, ks stride 1024 B
  const char* const wB = (const char*)w2opt + ((size_t)(bn*16 + wid*2))*65536 + (size_t)l*16;

#define MM4R01(A0_,A1_,B0_,B1_) do{ __builtin_amdgcn_s_setprio(1);              \
    acc[0][0]=mfma32(A0_,B0_,acc[0][0]); acc[0][1]=mfma32(A0_,B1_,acc[0][1]);   \
    acc[1][0]=mfma32(A1_,B0_,acc[1][0]); acc[1][1]=mfma32(A1_,B1_,acc[1][1]);   \
    __builtin_amdgcn_s_setprio(0); }while(0)
#define MM4R23(A2_,A3_,B0_,B1_) do{ __builtin_amdgcn_s_setprio(1);              \
    acc[2][0]=mfma32(A2_,B0_,acc[2][0]); acc[2][1]=mfma32(A2_,B1_,acc[2][1]);   \
    acc[3][0]=mfma32(A3_,B0_,acc[3][0]); acc[3][1]=mfma32(A3_,B1_,acc[3][1]);   \
    __builtin_amdgcn_s_setprio(0); }while(0)

  for (int h = 0; h < 2; ++h){
    const char* pbB = wB + h*32768;       // base of this half's B (tile0); tile1 = +65536
    bf16x8 Be0, Be1, Bo0, Bo1;
    Be0 = ld16(pbB);                      // B ks0 — flies under GEMM1
    Be1 = ld16(pbB + 65536);

    // ---- GEMM1 half h: h1[128][512] = relu(l1 @ W1[h*512..+512]^T + b1), 2 passes
#pragma unroll
    for (int p = 0; p < 2; ++p){
      f32x16 c4[4];
#pragma unroll
      for (int mt = 0; mt < 4; ++mt) c4[mt] = zero16();
#pragma unroll
      for (int ks = 0; ks < 2; ++ks){
        bf16x8 bw = ld16(w1opt + (((size_t)((h*16 + p*8 + wid)*2 + ks))*64 + l)*8);
#pragma unroll
        for (int mt = 0; mt < 4; ++mt){
          bf16x8 aw = ld16(l1p + (mt*32 + l31)*L1S + ks*32 + lh*16);
          c4[mt] = mfma32(aw, bw, c4[mt]);
        }
      }
      const int colh = p*256 + wid*32 + l31;
      const float bv = b1[h*512 + colh];
#pragma unroll
      for (int mt = 0; mt < 4; ++mt)
#pragma unroll
        for (int r = 0; r < 16; ++r){
          const int row = mt*32 + (r & 3) + 8*(r >> 2) + 4*lh;
          *(unsigned short*)(h1 + row*H1S + colh*2) = f2bf(fmaxf(c4[mt][r] + bv, 0.f));
        }
    }
    __syncthreads();

    // ---- GEMM2 half h: 32 ks, MM4 pipeline (R8 schedule, operands swapped)
    {
      bf16x8 A0e, A1e, A2e, A3e, A0o, A1o, A2o, A3o;
      const char* pb0 = pbB;              // bumped +2048/iter
      const char* pb1 = pbB + 65536;

      // prologue: A rows01+rows23 @ ks0, A rows01 @ ks1  (Be already in flight)
      A0e = ld16(h1 + a0o);      A1e = ld16(h1 + a1o);
      A2e = ld16(h1 + a2o);      A3e = ld16(h1 + a3o);
      A0o = ld16(h1 + a0o + 32); A1o = ld16(h1 + a1o + 32);

#pragma unroll
      for (int t = 0; t < 15; ++t){
        const int ka = t*64;              // A imm byte base for ks=2t (16-bit ds imm)
        A2o = ld16(h1 + a2o + ka + 32);  A3o = ld16(h1 + a3o + ka + 32);   // A rows23 ks+1
        Bo0 = ld16(pb0 + 1024);          Bo1 = ld16(pb1 + 1024);          // B ks+1
        MM4R01(A0e, A1e, Be0, Be1);                                       // ks rows 0-63
        A0e = ld16(h1 + a0o + ka + 64);  A1e = ld16(h1 + a1o + ka + 64);  // A rows01 ks+2
        MM4R23(A2e, A3e, Be0, Be1);                                       // ks rows 64-127
        A2e = ld16(h1 + a2o + ka + 64);  A3e = ld16(h1 + a3o + ka + 64);  // A rows23 ks+2
        Be0 = ld16(pb0 + 2048);          Be1 = ld16(pb1 + 2048);          // B ks+2
        MM4R01(A0o, A1o, Bo0, Bo1);                                       // ks+1 rows 0-63
        A0o = ld16(h1 + a0o + ka + 96);  A1o = ld16(h1 + a1o + ka + 96);  // A rows01 ks+3
        MM4R23(A2o, A3o, Bo0, Bo1);                                       // ks+1 rows 64-127
        pb0 += 2048; pb1 += 2048;
      }
      // epilogue: ks 30,31 (A0e/A1e/A2e/A3e=ks30, Be=ks30, A0o/A1o=ks31 from t=14)
      A2o = ld16(h1 + a2o + 992);  A3o = ld16(h1 + a3o + 992);            // A rows23 ks31
      Bo0 = ld16(pb0 + 1024);      Bo1 = ld16(pb1 + 1024);                // B ks31
      MM4R01(A0e, A1e, Be0, Be1);
      MM4R23(A2e, A3e, Be0, Be1);
      MM4R01(A0o, A1o, Bo0, Bo1);
      MM4R23(A2o, A3o, Bo0, Bo1);
    }
    __syncthreads();                      // done reading h1; next half overwrites
  }
#undef MM4R01
#undef MM4R23

  // ---- epilogue: h2 = relu(acc + b2); per-wave partial logits over its 64 cols;
  //      lane-reduce over l31; stage sp[wid][128][3] (overlays dead l1p/h1);
  //      cross-wave sum -> pws[bn].  (R12-verified logic.)
  float* sp = (float*)smem;
  {
    float b2v[2], w30[2], w31[2], w32[2];
#pragma unroll
    for (int nt = 0; nt < 2; ++nt){
      const int colg = bn*512 + wid*64 + nt*32 + l31;
      b2v[nt] = b2[colg];
      w30[nt] = W3[0*NEUR + colg];
      w31[nt] = W3[1*NEUR + colg];
      w32[nt] = W3[2*NEUR + colg];
    }
#pragma unroll
    for (int mt = 0; mt < 4; ++mt){
      float p0[16], p1[16], p2[16];
#pragma unroll
      for (int r = 0; r < 16; ++r){ p0[r] = 0.f; p1[r] = 0.f; p2[r] = 0.f; }
#pragma unroll
      for (int nt = 0; nt < 2; ++nt)
#pragma unroll
        for (int r = 0; r < 16; ++r){
          const float hv = fmaxf(acc[mt][nt][r] + b2v[nt], 0.f);
          p0[r] += hv * w30[nt];
          p1[r] += hv * w31[nt];
          p2[r] += hv * w32[nt];
        }
#pragma unroll
      for (int off = 1; off < 32; off <<= 1)
#pragma unroll
        for (int r = 0; r < 16; ++r){
          p0[r] += __shfl_xor(p0[r], off, 64);
          p1[r] += __shfl_xor(p1[r], off, 64);
          p2[r] += __shfl_xor(p2[r], off, 64);
        }
      if (l31 == 0){
#pragma unroll
        for (int r = 0; r < 16; ++r){
          const int row = mt*32 + (r & 3) + 8*(r >> 2) + 4*lh;
          float* d = sp + ((size_t)wid*BM + row)*3;
          d[0] = p0[r]; d[1] = p1[r]; d[2] = p2[r];
        }
      }
    }
  }
  __syncthreads();

  for (int t2 = tid; t2 < BM*3; t2 += THREADS){
    const int row = t2 / 3, j = t2 - row*3;
    float v = 0.f;
#pragma unroll
    for (int w = 0; w < 8; ++w) v += sp[((size_t)w*BM + row)*3 + j];
    pws[((size_t)bn*batch + rbase + row)*3 + j] = v;
  }
}

// ---------- fallback (ws too small): round-8 kernel, direct W2 reads ----------
__global__ __launch_bounds__(THREADS, 2) void mlp_kernel_old(
    const float* __restrict__ x,
    const float* __restrict__ Wx, const float* __restrict__ bxp,
    const float* __restrict__ Wu, const float* __restrict__ bup,
    const float* __restrict__ W1, const float* __restrict__ b1,
    const float* __restrict__ W2f, const float* __restrict__ b2,
    const float* __restrict__ W3, const float* __restrict__ b3,
    float* __restrict__ out)
{
  extern __shared__ char smem[];
  unsigned short* l1p = (unsigned short*)smem;
  char* h1 = smem + 5120;   // 64 x 2064
  const int tid = threadIdx.x, l = tid & 63, wid = tid >> 6;
  const int l31 = l & 31, lh = l >> 5;
  const long rbase = (long)blockIdx.x * 64;

  float* xs = (float*)h1;
  for (int i = tid; i < 64*25; i += THREADS) xs[i] = x[rbase*25 + i];
  __syncthreads();
  if (tid < 64){
    const float* xr = xs + tid*25;
    float l1v[10];
#pragma unroll
    for (int g = 0; g < 3; ++g)
#pragma unroll
      for (int o = 0; o < 2; ++o){
        float s = bxp[o];
#pragma unroll
        for (int i = 0; i < 5; ++i) s += xr[g + 3*i] * Wx[o*5 + i];
        l1v[g*2 + o] = fmaxf(s, 0.f);
      }
#pragma unroll
    for (int g = 0; g < 2; ++g)
#pragma unroll
      for (int o = 0; o < 2; ++o){
        float s = bup[o];
#pragma unroll
        for (int i = 0; i < 5; ++i) s += xr[15 + g + 2*i] * Wu[o*5 + i];
        l1v[6 + g*2 + o] = fmaxf(s, 0.f);
      }
    unsigned short* dst = l1p + tid*40;
#pragma unroll
    for (int i = 0; i < 10; ++i) dst[i] = f2bf(l1v[i]);
#pragma unroll
    for (int i = 10; i < 32; ++i) dst[i] = 0;
  }
  __syncthreads();

  f32x16 c[2][4];
#pragma unroll
  for (int mt = 0; mt < 2; ++mt)
#pragma unroll
    for (int nt = 0; nt < 4; ++nt) c[mt][nt] = zero16();
#pragma unroll
  for (int ks = 0; ks < 2; ++ks){
    bf16x8 a0 = ld16(smem + l31*80 + ks*32 + lh*16);
    bf16x8 a1 = ld16(smem + (32 + l31)*80 + ks*32 + lh*16);
#pragma unroll
    for (int nt = 0; nt < 4; ++nt){
      const int col = wid*128 + nt*32 + l31;
      s16x8 raw;
#pragma unroll
      for (int j = 0; j < 8; ++j){
        const int k = ks*16 + lh*8 + j;
        raw[j] = (k < 10) ? (short)f2bf(W1[col*10 + k]) : (short)0;
      }
      bf16x8 b = __builtin_bit_cast(bf16x8, raw);
      c[0][nt] = mfma32(a0, b, c[0][nt]);
      c[1][nt] = mfma32(a1, b, c[1][nt]);
    }
  }
#pragma unroll
  for (int nt = 0; nt < 4; ++nt){
    const int col = wid*128 + nt*32 + l31;
    const float bv = b1[col];
#pragma unroll
    for (int mt = 0; mt < 2; ++mt)
#pragma unroll
      for (int r = 0; r < 16; ++r){
        const int row = mt*32 + (r & 3) + 8*(r >> 2) + 4*lh;
        *reinterpret_cast<unsigned short*>(h1 + row*2064 + col*2) =
            f2bf(fmaxf(c[mt][nt][r] + bv, 0.f));
      }
  }
  __syncthreads();

  f32x16 acc[2][4];
#pragma unroll
  for (int mt = 0; mt < 2; ++mt)
#pragma unroll
    for (int nt = 0; nt < 4; ++nt) acc[mt][nt] = zero16();
  const int aA0 = l31*2064 + lh*16;
  for (int ks = 0; ks < 64; ++ks){
    bf16x8 A0 = ld16(h1 + aA0 + ks*32);
    bf16x8 A1 = ld16(h1 + aA0 + 32*2064 + ks*32);
#pragma unroll
    for (int nt = 0; nt < 4; ++nt){
      const int col = wid*128 + nt*32 + l31;
      const float* p = W2f + (size_t)col*NEUR + ks*16 + lh*8;
      s16x8 raw;
#pragma unroll
      for (int j = 0; j < 8; ++j) raw[j] = (short)f2bf(p[j]);
      bf16x8 B = __builtin_bit_cast(bf16x8, raw);
      acc[0][nt] = mfma32(A0, B, acc[0][nt]);
      acc[1][nt] = mfma32(A1, B, acc[1][nt]);
    }
  }
  __syncthreads();
#pragma unroll
  for (int nt = 0; nt < 4; ++nt){
    const int col = wid*128 + nt*32 + l31;
    const float bv = b2[col];
#pragma unroll
    for (int mt = 0; mt < 2; ++mt)
#pragma unroll
      for (int r = 0; r < 16; ++r){
        const int row = mt*32 + (r & 3) + 8*(r >> 2) + 4*lh;
        *reinterpret_cast<unsigned short*>(h1 + row*2064 + col*2) =
            f2bf(fmaxf(acc[mt][nt][r] + bv, 0.f));
      }
  }
  __syncthreads();
  float s[8][3];
#pragma unroll
  for (int rr = 0; rr < 8; ++rr)
#pragma unroll
    for (int j = 0; j < 3; ++j) s[rr][j] = 0.f;
#pragma unroll
  for (int h = 0; h < 2; ++h){
    const int k0 = h*512 + l*8;
    float w3v[3][8];
#pragma unroll
    for (int j = 0; j < 3; ++j)
#pragma unroll
      for (int i = 0; i < 8; ++i) w3v[j][i] = W3[j*NEUR + k0 + i];
#pragma unroll
    for (int rr = 0; rr < 8; ++rr){
      const int row = wid*8 + rr;
      s16x8 raw = *reinterpret_cast<const s16x8*>(h1 + row*2064 + k0*2);
#pragma unroll
      for (int i = 0; i < 8; ++i){
        const float hv = bf2f((unsigned short)raw[i]);
        s[rr][0] += hv * w3v[0][i];
        s[rr][1] += hv * w3v[1][i];
        s[rr][2] += hv * w3v[2][i];
      }
    }
  }
#pragma unroll
  for (int off = 1; off < 64; off <<= 1)
#pragma unroll
    for (int rr = 0; rr < 8; ++rr)
#pragma unroll
      for (int j = 0; j < 3; ++j) s[rr][j] += __shfl_xor(s[rr][j], off, 64);
  if (l == 0){
#pragma unroll
    for (int rr = 0; rr < 8; ++rr){
      const int row = wid*8 + rr;
#pragma unroll
      for (int j = 0; j < 3; ++j)
        out[(rbase + row)*3 + j] = 1.f / (1.f + __expf(-(s[rr][j] + b3[j])));
    }
  }
}

extern "C" void kernel_launch(void* const* d_in, const int* in_sizes, int n_in,
                              void* d_out, int out_size, void* d_ws, size_t ws_size,
                              hipStream_t stream){
  const float* x  = (const float*)d_in[0];
  const float* Wx = (const float*)d_in[1];
  const float* bx = (const float*)d_in[2];
  const float* Wu = (const float*)d_in[3];
  const float* bu = (const float*)d_in[4];
  const float* W1 = (const float*)d_in[5];
  const float* b1 = (const float*)d_in[6];
  const float* W2 = (const float*)d_in[7];
  const float* b2 = (const float*)d_in[8];
  const float* W3 = (const float*)d_in[9];
  const float* b3 = (const float*)d_in[10];
  float* out = (float*)d_out;

  const int batch = in_sizes[0] / 25;
  const size_t w2_bytes  = (size_t)NEUR*NEUR*2;          // 2 MB
  const size_t w1_bytes  = (size_t)4096*8*2;             // 64 KB
  const size_t pws_bytes = (size_t)batch*3*2*4;          // 3.1 MB
  const size_t ws_need   = w2_bytes + w1_bytes + pws_bytes;

  if (ws_size >= ws_need && (batch % BM) == 0){
    unsigned short* w2opt = (unsigned short*)d_ws;
    unsigned short* w1opt = (unsigned short*)((char*)d_ws + w2_bytes);
    float* pws            = (float*)((char*)d_ws + w2_bytes + w1_bytes);

    prep_kernel<<<512, 256, 0, stream>>>(W1, W2, w2opt, w1opt);

    const int smem = BM*L1S + BM*H1S;   // 10240 + 133120 = 143360 B
    hipFuncSetAttribute(reinterpret_cast<const void*>(mlp_kernel),
                        hipFuncAttributeMaxDynamicSharedMemorySize, smem);
    const int nblocks = (batch / BM) * 2;
    mlp_kernel<<<nblocks, THREADS, smem, stream>>>(
        x, Wx, bx, Wu, bu, b1, b2, W3, w2opt, w1opt, pws, batch);

    finish_kernel<<<(batch*3 + 255)/256, 256, 0, stream>>>(pws, b3, out, batch);
  } else {
    const int smem = 5120 + 64*2064;
    hipFuncSetAttribute(reinterpret_cast<const void*>(mlp_kernel_old),
                        hipFuncAttributeMaxDynamicSharedMemorySize, smem);
    mlp_kernel_old<<<batch/64, THREADS, smem, stream>>>(
        x, Wx, bx, Wu, bu, W1, b1, W2, b2, W3, b3, out);
  }
}

// Round 14
// 455.661 us; speedup vs baseline: 1.0015x; 1.0015x over previous
//
#include <hip/hip_runtime.h>
#include <stdint.h>

#define NEUR 1024
#define BM 128            // rows per block
#define THREADS 512
#define H1S 1040          // h1 half row stride bytes (512 bf16 + 16B pad)
#define L1S 80            // l1p row stride bytes

typedef short  s16x8  __attribute__((ext_vector_type(8)));
typedef __bf16 bf16x8 __attribute__((ext_vector_type(8)));
typedef float  f32x16 __attribute__((ext_vector_type(16)));

__device__ __forceinline__ unsigned short f2bf(float f){
  unsigned u = __builtin_bit_cast(unsigned, f);
  u += 0x7FFFu + ((u >> 16) & 1u);          // round-to-nearest-even
  return (unsigned short)(u >> 16);
}
__device__ __forceinline__ float bf2f(unsigned short h){
  unsigned u = ((unsigned)h) << 16;
  return __builtin_bit_cast(float, u);
}
__device__ __forceinline__ f32x16 mfma32(bf16x8 a, bf16x8 b, f32x16 c){
  return __builtin_amdgcn_mfma_f32_32x32x16_bf16(a, b, c, 0, 0, 0);
}
__device__ __forceinline__ f32x16 zero16(){
  f32x16 v;
#pragma unroll
  for (int r = 0; r < 16; ++r) v[r] = 0.f;
  return v;
}
__device__ __forceinline__ bf16x8 ld16(const void* p){
  return __builtin_bit_cast(bf16x8, *reinterpret_cast<const s16x8*>(p));
}

// Pre-swizzle weights into MFMA-fragment order (coalesced GEMM loads).
// w2opt[((nt*64 + ks)*64 + l)*8 + j] = bf16(W2[nt*32 + (l&31)][ks*16 + (l>>5)*8 + j])
// w1opt[((nt*2  + ks)*64 + l)*8 + j] = bf16(W1 padded to K=32, same fragment map)
__global__ void prep_kernel(const float* __restrict__ W1, const float* __restrict__ W2,
                            unsigned short* __restrict__ w2opt, unsigned short* __restrict__ w1opt){
  const int nchunks = NEUR * 128;
  const int total = nchunks + 4096;
  for (int i = blockIdx.x*blockDim.x + threadIdx.x; i < total; i += gridDim.x*blockDim.x){
    if (i < nchunks){
      const int col = i >> 7, c8 = i & 127;
      const float* src = W2 + (size_t)col*NEUR + c8*8;
      const int ks = c8 >> 1, lf = c8 & 1, lane = lf*32 + (col & 31), nt = col >> 5;
      unsigned short* dst = w2opt + (((size_t)(nt*64 + ks)*64 + lane) * 8);
#pragma unroll
      for (int j = 0; j < 8; ++j) dst[j] = f2bf(src[j]);
    } else {
      const int o = i - nchunks;
      const int nt = o >> 7, ks = (o >> 6) & 1, lane = o & 63;
      const int col = nt*32 + (lane & 31);
      unsigned short* dst = w1opt + (size_t)o * 8;
#pragma unroll
      for (int j = 0; j < 8; ++j){
        const int k = ks*16 + (lane >> 5)*8 + j;
        dst[j] = (k < 10) ? f2bf(W1[col*10 + k]) : (unsigned short)0;
      }
    }
  }
}

// finish: out = sigmoid(partial[0] + partial[1] + b3)
__global__ void finish_kernel(const float* __restrict__ pws, const float* __restrict__ b3,
                              float* __restrict__ out, int batch){
  const int total = batch * 3;
  for (int i = blockIdx.x*blockDim.x + threadIdx.x; i < total; i += gridDim.x*blockDim.x){
    const int j = i - (i/3)*3;
    const float v = pws[i] + pws[(size_t)total + i] + b3[j];
    out[i] = 1.f / (1.f + __expf(-v));
  }
}

// Main fused kernel: BM=128 x 512 cols per block; K split into 2 halves of 512.
// Wave tile = 128 rows x 64 cols: per K-step per wave 2 global B frags (TCP 50%)
// + 4 LDS A frags. GEMM2 = rolled MM4 pipeline (R8 register envelope).
__global__ __launch_bounds__(THREADS, 2) void mlp_kernel(
    const float* __restrict__ x,
    const float* __restrict__ Wx, const float* __restrict__ bxp,
    const float* __restrict__ Wu, const float* __restrict__ bup,
    const float* __restrict__ b1, const float* __restrict__ b2,
    const float* __restrict__ W3,
    const unsigned short* __restrict__ w2opt, const unsigned short* __restrict__ w1opt,
    float* __restrict__ pws, int batch)
{
  extern __shared__ char smem[];
  char* l1p = smem;                       // [128][L1S] 10240 B (dead after last GEMM1)
  char* h1  = smem + BM*L1S;              // [128][H1S] 133120 B  (total 143360)

  const int tid = threadIdx.x;
  const int l   = tid & 63;
  const int wid = tid >> 6;               // 8 waves; wave owns cols wid*64..+64, all 128 rows
  const int l31 = l & 31;
  const int lh  = l >> 5;
  const int bm  = blockIdx.x >> 1;
  const int bn  = blockIdx.x & 1;
  const long rbase = (long)bm * BM;

  // ---- 1. stage x tile (128*25 f32) into h1 region
  float* xs = (float*)h1;
  for (int i = tid; i < BM*25; i += THREADS) xs[i] = x[rbase*25 + i];
  __syncthreads();

  // ---- 2. l1 features (f32 exact), bf16-pad to K=32
  if (tid < BM){
    const float* xr = xs + tid*25;
    float l1v[10];
#pragma unroll
    for (int g = 0; g < 3; ++g)
#pragma unroll
      for (int o = 0; o < 2; ++o){
        float s = bxp[o];
#pragma unroll
        for (int i = 0; i < 5; ++i) s += xr[g + 3*i] * Wx[o*5 + i];
        l1v[g*2 + o] = fmaxf(s, 0.f);
      }
#pragma unroll
    for (int g = 0; g < 2; ++g)
#pragma unroll
      for (int o = 0; o < 2; ++o){
        float s = bup[o];
#pragma unroll
        for (int i = 0; i < 5; ++i) s += xr[15 + g + 2*i] * Wu[o*5 + i];
        l1v[6 + g*2 + o] = fmaxf(s, 0.f);
      }
    unsigned short* dst = (unsigned short*)(l1p + tid*L1S);
#pragma unroll
    for (int i = 0; i < 10; ++i) dst[i] = f2bf(l1v[i]);
#pragma unroll
    for (int i = 10; i < 32; ++i) dst[i] = 0;
  }
  __syncthreads();

  // ---- persistent GEMM2 accumulators: wave tile 128 rows x 64 cols
  f32x16 acc[4][2];                       // [row-tile mt][col-tile nt]
#pragma unroll
  for (int mt = 0; mt < 4; ++mt)
#pragma unroll
    for (int nt = 0; nt < 2; ++nt) acc[mt][nt] = zero16();

  // A fragment row bases in h1
  const int a0o = (0*32 + l31)*H1S + lh*16;
  const int a1o = (1*32 + l31)*H1S + lh*16;
  const int a2o = (2*32 + l31)*H1S + lh*16;
  const int a3o = (3*32 + l31)*H1S + lh*16;

  // wave's two B n-tiles; tile stride 65536 B, ks stride 1024 B
  const char* const wB = (const char*)w2opt + ((size_t)(bn*16 + wid*2))*65536 + (size_t)l*16;

#define MM4R01(A0_,A1_,B0_,B1_) do{ __builtin_amdgcn_s_setprio(1);              \
    acc[0][0]=mfma32(A0_,B0_,acc[0][0]); acc[0][1]=mfma32(A0_,B1_,acc[0][1]);   \
    acc[1][0]=mfma32(A1_,B0_,acc[1][0]); acc[1][1]=mfma32(A1_,B1_,acc[1][1]);   \
    __builtin_amdgcn_s_setprio(0); }while(0)
#define MM4R23(A2_,A3_,B0_,B1_) do{ __builtin_amdgcn_s_setprio(1);              \
    acc[2][0]=mfma32(A2_,B0_,acc[2][0]); acc[2][1]=mfma32(A2_,B1_,acc[2][1]);   \
    acc[3][0]=mfma32(A3_,B0_,acc[3][0]); acc[3][1]=mfma32(A3_,B1_,acc[3][1]);   \
    __builtin_amdgcn_s_setprio(0); }while(0)

  for (int h = 0; h < 2; ++h){
    const char* pbB = wB + h*32768;       // base of this half's B (tile0); tile1 = +65536
    bf16x8 Be0, Be1, Bo0, Bo1;
    Be0 = ld16(pbB);                      // B ks0 — flies under GEMM1
    Be1 = ld16(pbB + 65536);

    // ---- GEMM1 half h: h1[128][512] = relu(l1 @ W1[h*512..+512]^T + b1), 2 passes
#pragma unroll
    for (int p = 0; p < 2; ++p){
      f32x16 c4[4];
#pragma unroll
      for (int mt = 0; mt < 4; ++mt) c4[mt] = zero16();
#pragma unroll
      for (int ks = 0; ks < 2; ++ks){
        bf16x8 bw = ld16(w1opt + (((size_t)((h*16 + p*8 + wid)*2 + ks))*64 + l)*8);
#pragma unroll
        for (int mt = 0; mt < 4; ++mt){
          bf16x8 aw = ld16(l1p + (mt*32 + l31)*L1S + ks*32 + lh*16);
          c4[mt] = mfma32(aw, bw, c4[mt]);
        }
      }
      const int colh = p*256 + wid*32 + l31;
      const float bv = b1[h*512 + colh];
#pragma unroll
      for (int mt = 0; mt < 4; ++mt)
#pragma unroll
        for (int r = 0; r < 16; ++r){
          const int row = mt*32 + (r & 3) + 8*(r >> 2) + 4*lh;
          *(unsigned short*)(h1 + row*H1S + colh*2) = f2bf(fmaxf(c4[mt][r] + bv, 0.f));
        }
    }
    __syncthreads();

    // ---- GEMM2 half h: 32 ks, rolled MM4 pipeline (R8 register envelope)
    {
      bf16x8 A0e, A1e, A2e, A3e, A0o, A1o, A2o, A3o;
      const char* pb0 = pbB;              // bumped +2048/iter
      const char* pb1 = pbB + 65536;
      int ao = 0;                         // A byte offset for ks=2t, bumped +64/iter

      // prologue: A rows @ ks0, A rows01 @ ks1  (Be already in flight)
      A0e = ld16(h1 + a0o);      A1e = ld16(h1 + a1o);
      A2e = ld16(h1 + a2o);      A3e = ld16(h1 + a3o);
      A0o = ld16(h1 + a0o + 32); A1o = ld16(h1 + a1o + 32);

      for (int t = 0; t < 15; ++t){       // rolled — keeps live set ~108 VGPR
        A2o = ld16(h1 + a2o + ao + 32);  A3o = ld16(h1 + a3o + ao + 32);   // A rows23 ks+1
        Bo0 = ld16(pb0 + 1024);          Bo1 = ld16(pb1 + 1024);          // B ks+1
        MM4R01(A0e, A1e, Be0, Be1);                                       // ks rows 0-63
        A0e = ld16(h1 + a0o + ao + 64);  A1e = ld16(h1 + a1o + ao + 64);  // A rows01 ks+2
        MM4R23(A2e, A3e, Be0, Be1);                                       // ks rows 64-127
        A2e = ld16(h1 + a2o + ao + 64);  A3e = ld16(h1 + a3o + ao + 64);  // A rows23 ks+2
        Be0 = ld16(pb0 + 2048);          Be1 = ld16(pb1 + 2048);          // B ks+2
        MM4R01(A0o, A1o, Bo0, Bo1);                                       // ks+1 rows 0-63
        A0o = ld16(h1 + a0o + ao + 96);  A1o = ld16(h1 + a1o + ao + 96);  // A rows01 ks+3
        MM4R23(A2o, A3o, Bo0, Bo1);                                       // ks+1 rows 64-127
        pb0 += 2048; pb1 += 2048; ao += 64;
      }
      // epilogue: ks 30,31 (Ae*/Be = ks30; A0o/A1o = ks31 from t=14; ao = 960)
      A2o = ld16(h1 + a2o + ao + 32);  A3o = ld16(h1 + a3o + ao + 32);    // A rows23 ks31
      Bo0 = ld16(pb0 + 1024);          Bo1 = ld16(pb1 + 1024);            // B ks31
      MM4R01(A0e, A1e, Be0, Be1);
      MM4R23(A2e, A3e, Be0, Be1);
      MM4R01(A0o, A1o, Bo0, Bo1);
      MM4R23(A2o, A3o, Bo0, Bo1);
    }
    __syncthreads();                      // done reading h1; next half overwrites
  }
#undef MM4R01
#undef MM4R23

  // ---- epilogue: h2 = relu(acc + b2); per-wave partial logits over its 64 cols;
  //      lane-reduce over l31; stage sp[wid][128][3] (overlays dead l1p/h1);
  //      cross-wave sum -> pws[bn].  (R12-verified logic.)
  float* sp = (float*)smem;
  {
    float b2v[2], w30[2], w31[2], w32[2];
#pragma unroll
    for (int nt = 0; nt < 2; ++nt){
      const int colg = bn*512 + wid*64 + nt*32 + l31;
      b2v[nt] = b2[colg];
      w30[nt] = W3[0*NEUR + colg];
      w31[nt] = W3[1*NEUR + colg];
      w32[nt] = W3[2*NEUR + colg];
    }
#pragma unroll
    for (int mt = 0; mt < 4; ++mt){
      float p0[16], p1[16], p2[16];
#pragma unroll
      for (int r = 0; r < 16; ++r){ p0[r] = 0.f; p1[r] = 0.f; p2[r] = 0.f; }
#pragma unroll
      for (int nt = 0; nt < 2; ++nt)
#pragma unroll
        for (int r = 0; r < 16; ++r){
          const float hv = fmaxf(acc[mt][nt][r] + b2v[nt], 0.f);
          p0[r] += hv * w30[nt];
          p1[r] += hv * w31[nt];
          p2[r] += hv * w32[nt];
        }
#pragma unroll
      for (int off = 1; off < 32; off <<= 1)
#pragma unroll
        for (int r = 0; r < 16; ++r){
          p0[r] += __shfl_xor(p0[r], off, 64);
          p1[r] += __shfl_xor(p1[r], off, 64);
          p2[r] += __shfl_xor(p2[r], off, 64);
        }
      if (l31 == 0){
#pragma unroll
        for (int r = 0; r < 16; ++r){
          const int row = mt*32 + (r & 3) + 8*(r >> 2) + 4*lh;
          float* d = sp + ((size_t)wid*BM + row)*3;
          d[0] = p0[r]; d[1] = p1[r]; d[2] = p2[r];
        }
      }
    }
  }
  __syncthreads();

  for (int t2 = tid; t2 < BM*3; t2 += THREADS){
    const int row = t2 / 3, j = t2 - row*3;
    float v = 0.f;
#pragma unroll
    for (int w = 0; w < 8; ++w) v += sp[((size_t)w*BM + row)*3 + j];
    pws[((size_t)bn*batch + rbase + row)*3 + j] = v;
  }
}

// ---------- fallback (ws too small): round-8 kernel, direct W2 reads ----------
__global__ __launch_bounds__(THREADS, 2) void mlp_kernel_old(
    const float* __restrict__ x,
    const float* __restrict__ Wx, const float* __restrict__ bxp,
    const float* __restrict__ Wu, const float* __restrict__ bup,
    const float* __restrict__ W1, const float* __restrict__ b1,
    const float* __restrict__ W2f, const float* __restrict__ b2,
    const float* __restrict__ W3, const float* __restrict__ b3,
    float* __restrict__ out)
{
  extern __shared__ char smem[];
  unsigned short* l1p = (unsigned short*)smem;
  char* h1 = smem + 5120;   // 64 x 2064
  const int tid = threadIdx.x, l = tid & 63, wid = tid >> 6;
  const int l31 = l & 31, lh = l >> 5;
  const long rbase = (long)blockIdx.x * 64;

  float* xs = (float*)h1;
  for (int i = tid; i < 64*25; i += THREADS) xs[i] = x[rbase*25 + i];
  __syncthreads();
  if (tid < 64){
    const float* xr = xs + tid*25;
    float l1v[10];
#pragma unroll
    for (int g = 0; g < 3; ++g)
#pragma unroll
      for (int o = 0; o < 2; ++o){
        float s = bxp[o];
#pragma unroll
        for (int i = 0; i < 5; ++i) s += xr[g + 3*i] * Wx[o*5 + i];
        l1v[g*2 + o] = fmaxf(s, 0.f);
      }
#pragma unroll
    for (int g = 0; g < 2; ++g)
#pragma unroll
      for (int o = 0; o < 2; ++o){
        float s = bup[o];
#pragma unroll
        for (int i = 0; i < 5; ++i) s += xr[15 + g + 2*i] * Wu[o*5 + i];
        l1v[6 + g*2 + o] = fmaxf(s, 0.f);
      }
    unsigned short* dst = l1p + tid*40;
#pragma unroll
    for (int i = 0; i < 10; ++i) dst[i] = f2bf(l1v[i]);
#pragma unroll
    for (int i = 10; i < 32; ++i) dst[i] = 0;
  }
  __syncthreads();

  f32x16 c[2][4];
#pragma unroll
  for (int mt = 0; mt < 2; ++mt)
#pragma unroll
    for (int nt = 0; nt < 4; ++nt) c[mt][nt] = zero16();
#pragma unroll
  for (int ks = 0; ks < 2; ++ks){
    bf16x8 a0 = ld16(smem + l31*80 + ks*32 + lh*16);
    bf16x8 a1 = ld16(smem + (32 + l31)*80 + ks*32 + lh*16);
#pragma unroll
    for (int nt = 0; nt < 4; ++nt){
      const int col = wid*128 + nt*32 + l31;
      s16x8 raw;
#pragma unroll
      for (int j = 0; j < 8; ++j){
        const int k = ks*16 + lh*8 + j;
        raw[j] = (k < 10) ? (short)f2bf(W1[col*10 + k]) : (short)0;
      }
      bf16x8 b = __builtin_bit_cast(bf16x8, raw);
      c[0][nt] = mfma32(a0, b, c[0][nt]);
      c[1][nt] = mfma32(a1, b, c[1][nt]);
    }
  }
#pragma unroll
  for (int nt = 0; nt < 4; ++nt){
    const int col = wid*128 + nt*32 + l31;
    const float bv = b1[col];
#pragma unroll
    for (int mt = 0; mt < 2; ++mt)
#pragma unroll
      for (int r = 0; r < 16; ++r){
        const int row = mt*32 + (r & 3) + 8*(r >> 2) + 4*lh;
        *reinterpret_cast<unsigned short*>(h1 + row*2064 + col*2) =
            f2bf(fmaxf(c[mt][nt][r] + bv, 0.f));
      }
  }
  __syncthreads();

  f32x16 acc[2][4];
#pragma unroll
  for (int mt = 0; mt < 2; ++mt)
#pragma unroll
    for (int nt = 0; nt < 4; ++nt) acc[mt][nt] = zero16();
  const int aA0 = l31*2064 + lh*16;
  for (int ks = 0; ks < 64; ++ks){
    bf16x8 A0 = ld16(h1 + aA0 + ks*32);
    bf16x8 A1 = ld16(h1 + aA0 + 32*2064 + ks*32);
#pragma unroll
    for (int nt = 0; nt < 4; ++nt){
      const int col = wid*128 + nt*32 + l31;
      const float* p = W2f + (size_t)col*NEUR + ks*16 + lh*8;
      s16x8 raw;
#pragma unroll
      for (int j = 0; j < 8; ++j) raw[j] = (short)f2bf(p[j]);
      bf16x8 B = __builtin_bit_cast(bf16x8, raw);
      acc[0][nt] = mfma32(A0, B, acc[0][nt]);
      acc[1][nt] = mfma32(A1, B, acc[1][nt]);
    }
  }
  __syncthreads();
#pragma unroll
  for (int nt = 0; nt < 4; ++nt){
    const int col = wid*128 + nt*32 + l31;
    const float bv = b2[col];
#pragma unroll
    for (int mt = 0; mt < 2; ++mt)
#pragma unroll
      for (int r = 0; r < 16; ++r){
        const int row = mt*32 + (r & 3) + 8*(r >> 2) + 4*lh;
        *reinterpret_cast<unsigned short*>(h1 + row*2064 + col*2) =
            f2bf(fmaxf(acc[mt][nt][r] + bv, 0.f));
      }
  }
  __syncthreads();
  float s[8][3];
#pragma unroll
  for (int rr = 0; rr < 8; ++rr)
#pragma unroll
    for (int j = 0; j < 3; ++j) s[rr][j] = 0.f;
#pragma unroll
  for (int h = 0; h < 2; ++h){
    const int k0 = h*512 + l*8;
    float w3v[3][8];
#pragma unroll
    for (int j = 0; j < 3; ++j)
#pragma unroll
      for (int i = 0; i < 8; ++i) w3v[j][i] = W3[j*NEUR + k0 + i];
#pragma unroll
    for (int rr = 0; rr < 8; ++rr){
      const int row = wid*8 + rr;
      s16x8 raw = *reinterpret_cast<const s16x8*>(h1 + row*2064 + k0*2);
#pragma unroll
      for (int i = 0; i < 8; ++i){
        const float hv = bf2f((unsigned short)raw[i]);
        s[rr][0] += hv * w3v[0][i];
        s[rr][1] += hv * w3v[1][i];
        s[rr][2] += hv * w3v[2][i];
      }
    }
  }
#pragma unroll
  for (int off = 1; off < 64; off <<= 1)
#pragma unroll
    for (int rr = 0; rr < 8; ++rr)
#pragma unroll
      for (int j = 0; j < 3; ++j) s[rr][j] += __shfl_xor(s[rr][j], off, 64);
  if (l == 0){
#pragma unroll
    for (int rr = 0; rr < 8; ++rr){
      const int row = wid*8 + rr;
#pragma unroll
      for (int j = 0; j < 3; ++j)
        out[(rbase + row)*3 + j] = 1.f / (1.f + __expf(-(s[rr][j] + b3[j])));
    }
  }
}

extern "C" void kernel_launch(void* const* d_in, const int* in_sizes, int n_in,
                              void* d_out, int out_size, void* d_ws, size_t ws_size,
                              hipStream_t stream){
  const float* x  = (const float*)d_in[0];
  const float* Wx = (const float*)d_in[1];
  const float* bx = (const float*)d_in[2];
  const float* Wu = (const float*)d_in[3];
  const float* bu = (const float*)d_in[4];
  const float* W1 = (const float*)d_in[5];
  const float* b1 = (const float*)d_in[6];
  const float* W2 = (const float*)d_in[7];
  const float* b2 = (const float*)d_in[8];
  const float* W3 = (const float*)d_in[9];
  const float* b3 = (const float*)d_in[10];
  float* out = (float*)d_out;

  const int batch = in_sizes[0] / 25;
  const size_t w2_bytes  = (size_t)NEUR*NEUR*2;          // 2 MB
  const size_t w1_bytes  = (size_t)4096*8*2;             // 64 KB
  const size_t pws_bytes = (size_t)batch*3*2*4;          // 3.1 MB
  const size_t ws_need   = w2_bytes + w1_bytes + pws_bytes;

  if (ws_size >= ws_need && (batch % BM) == 0){
    unsigned short* w2opt = (unsigned short*)d_ws;
    unsigned short* w1opt = (unsigned short*)((char*)d_ws + w2_bytes);
    float* pws            = (float*)((char*)d_ws + w2_bytes + w1_bytes);

    prep_kernel<<<512, 256, 0, stream>>>(W1, W2, w2opt, w1opt);

    const int smem = BM*L1S + BM*H1S;   // 10240 + 133120 = 143360 B
    hipFuncSetAttribute(reinterpret_cast<const void*>(mlp_kernel),
                        hipFuncAttributeMaxDynamicSharedMemorySize, smem);
    const int nblocks = (batch / BM) * 2;
    mlp_kernel<<<nblocks, THREADS, smem, stream>>>(
        x, Wx, bx, Wu, bu, b1, b2, W3, w2opt, w1opt, pws, batch);

    finish_kernel<<<(batch*3 + 255)/256, 256, 0, stream>>>(pws, b3, out, batch);
  } else {
    const int smem = 5120 + 64*2064;
    hipFuncSetAttribute(reinterpret_cast<const void*>(mlp_kernel_old),
                        hipFuncAttributeMaxDynamicSharedMemorySize, smem);
    mlp_kernel_old<<<batch/64, THREADS, smem, stream>>>(
        x, Wx, bx, Wu, bu, W1, b1, W2, b2, W3, b3, out);
  }
}

// Round 15
// 428.682 us; speedup vs baseline: 1.0645x; 1.0629x over previous
//
#include <hip/hip_runtime.h>
#include <stdint.h>

#define NEUR 1024
#define BM 128            // rows per block
#define THREADS 512
#define H1S 1040          // h1 half row stride bytes (512 bf16 + 16B pad)
#define L1S 80            // l1p row stride bytes

typedef short  s16x8  __attribute__((ext_vector_type(8)));
typedef __bf16 bf16x8 __attribute__((ext_vector_type(8)));
typedef float  f32x16 __attribute__((ext_vector_type(16)));

__device__ __forceinline__ unsigned short f2bf(float f){
  unsigned u = __builtin_bit_cast(unsigned, f);
  u += 0x7FFFu + ((u >> 16) & 1u);          // round-to-nearest-even
  return (unsigned short)(u >> 16);
}
__device__ __forceinline__ float bf2f(unsigned short h){
  unsigned u = ((unsigned)h) << 16;
  return __builtin_bit_cast(float, u);
}
__device__ __forceinline__ f32x16 mfma32(bf16x8 a, bf16x8 b, f32x16 c){
  return __builtin_amdgcn_mfma_f32_32x32x16_bf16(a, b, c, 0, 0, 0);
}
__device__ __forceinline__ f32x16 zero16(){
  f32x16 v;
#pragma unroll
  for (int r = 0; r < 16; ++r) v[r] = 0.f;
  return v;
}
__device__ __forceinline__ bf16x8 ld16(const void* p){
  return __builtin_bit_cast(bf16x8, *reinterpret_cast<const s16x8*>(p));
}

// Pre-swizzle weights into MFMA-fragment order (coalesced GEMM loads).
// w2opt[((nt*64 + ks)*64 + l)*8 + j] = bf16(W2[nt*32 + (l&31)][ks*16 + (l>>5)*8 + j])
// w1opt[((nt*2  + ks)*64 + l)*8 + j] = bf16(W1 padded to K=32, same fragment map)
__global__ void prep_kernel(const float* __restrict__ W1, const float* __restrict__ W2,
                            unsigned short* __restrict__ w2opt, unsigned short* __restrict__ w1opt){
  const int nchunks = NEUR * 128;
  const int total = nchunks + 4096;
  for (int i = blockIdx.x*blockDim.x + threadIdx.x; i < total; i += gridDim.x*blockDim.x){
    if (i < nchunks){
      const int col = i >> 7, c8 = i & 127;
      const float* src = W2 + (size_t)col*NEUR + c8*8;
      const int ks = c8 >> 1, lf = c8 & 1, lane = lf*32 + (col & 31), nt = col >> 5;
      unsigned short* dst = w2opt + (((size_t)(nt*64 + ks)*64 + lane) * 8);
#pragma unroll
      for (int j = 0; j < 8; ++j) dst[j] = f2bf(src[j]);
    } else {
      const int o = i - nchunks;
      const int nt = o >> 7, ks = (o >> 6) & 1, lane = o & 63;
      const int col = nt*32 + (lane & 31);
      unsigned short* dst = w1opt + (size_t)o * 8;
#pragma unroll
      for (int j = 0; j < 8; ++j){
        const int k = ks*16 + (lane >> 5)*8 + j;
        dst[j] = (k < 10) ? f2bf(W1[col*10 + k]) : (unsigned short)0;
      }
    }
  }
}

// finish: out = sigmoid(partial[0] + partial[1] + b3)
__global__ void finish_kernel(const float* __restrict__ pws, const float* __restrict__ b3,
                              float* __restrict__ out, int batch){
  const int total = batch * 3;
  for (int i = blockIdx.x*blockDim.x + threadIdx.x; i < total; i += gridDim.x*blockDim.x){
    const int j = i - (i/3)*3;
    const float v = pws[i] + pws[(size_t)total + i] + b3[j];
    out[i] = 1.f / (1.f + __expf(-v));
  }
}

// Main fused kernel: BM=128 x 512 cols per block; K split into 2 halves of 512.
// Wave tile = 128 rows x 64 cols (2 global B frags/K-step -> TCP at 50%).
// GEMM1 streamed per row-tile (16-reg accumulator) + rolled GEMM2 pipeline
// keep the register peak under the 256/wave cap (R13/R14 spilled here).
__global__ __launch_bounds__(THREADS, 2) void mlp_kernel(
    const float* __restrict__ x,
    const float* __restrict__ Wx, const float* __restrict__ bxp,
    const float* __restrict__ Wu, const float* __restrict__ bup,
    const float* __restrict__ b1, const float* __restrict__ b2,
    const float* __restrict__ W3,
    const unsigned short* __restrict__ w2opt, const unsigned short* __restrict__ w1opt,
    float* __restrict__ pws, int batch)
{
  extern __shared__ char smem[];
  char* l1p = smem;                       // [128][L1S] 10240 B (dead after last GEMM1)
  char* h1  = smem + BM*L1S;              // [128][H1S] 133120 B  (total 143360)

  const int tid = threadIdx.x;
  const int l   = tid & 63;
  const int wid = tid >> 6;               // 8 waves; wave owns cols wid*64..+64, all 128 rows
  const int l31 = l & 31;
  const int lh  = l >> 5;
  const int bm  = blockIdx.x >> 1;
  const int bn  = blockIdx.x & 1;
  const long rbase = (long)bm * BM;

  // ---- 1. stage x tile (128*25 f32) into h1 region
  float* xs = (float*)h1;
  for (int i = tid; i < BM*25; i += THREADS) xs[i] = x[rbase*25 + i];
  __syncthreads();

  // ---- 2. l1 features (f32 exact), bf16-pad to K=32
  if (tid < BM){
    const float* xr = xs + tid*25;
    float l1v[10];
#pragma unroll
    for (int g = 0; g < 3; ++g)
#pragma unroll
      for (int o = 0; o < 2; ++o){
        float s = bxp[o];
#pragma unroll
        for (int i = 0; i < 5; ++i) s += xr[g + 3*i] * Wx[o*5 + i];
        l1v[g*2 + o] = fmaxf(s, 0.f);
      }
#pragma unroll
    for (int g = 0; g < 2; ++g)
#pragma unroll
      for (int o = 0; o < 2; ++o){
        float s = bup[o];
#pragma unroll
        for (int i = 0; i < 5; ++i) s += xr[15 + g + 2*i] * Wu[o*5 + i];
        l1v[6 + g*2 + o] = fmaxf(s, 0.f);
      }
    unsigned short* dst = (unsigned short*)(l1p + tid*L1S);
#pragma unroll
    for (int i = 0; i < 10; ++i) dst[i] = f2bf(l1v[i]);
#pragma unroll
    for (int i = 10; i < 32; ++i) dst[i] = 0;
  }
  __syncthreads();

  // ---- persistent GEMM2 accumulators: wave tile 128 rows x 64 cols
  f32x16 acc[4][2];                       // [row-tile mt][col-tile nt]
#pragma unroll
  for (int mt = 0; mt < 4; ++mt)
#pragma unroll
    for (int nt = 0; nt < 2; ++nt) acc[mt][nt] = zero16();

  // A fragment row bases in h1
  const int a0o = (0*32 + l31)*H1S + lh*16;
  const int a1o = (1*32 + l31)*H1S + lh*16;
  const int a2o = (2*32 + l31)*H1S + lh*16;
  const int a3o = (3*32 + l31)*H1S + lh*16;

  // wave's two B n-tiles; tile stride 65536 B, ks stride 1024 B
  const char* const wB = (const char*)w2opt + ((size_t)(bn*16 + wid*2))*65536 + (size_t)l*16;

#define MM4R01(A0_,A1_,B0_,B1_) do{ __builtin_amdgcn_s_setprio(1);              \
    acc[0][0]=mfma32(A0_,B0_,acc[0][0]); acc[0][1]=mfma32(A0_,B1_,acc[0][1]);   \
    acc[1][0]=mfma32(A1_,B0_,acc[1][0]); acc[1][1]=mfma32(A1_,B1_,acc[1][1]);   \
    __builtin_amdgcn_s_setprio(0); }while(0)
#define MM4R23(A2_,A3_,B0_,B1_) do{ __builtin_amdgcn_s_setprio(1);              \
    acc[2][0]=mfma32(A2_,B0_,acc[2][0]); acc[2][1]=mfma32(A2_,B1_,acc[2][1]);   \
    acc[3][0]=mfma32(A3_,B0_,acc[3][0]); acc[3][1]=mfma32(A3_,B1_,acc[3][1]);   \
    __builtin_amdgcn_s_setprio(0); }while(0)

  for (int h = 0; h < 2; ++h){
    // ---- GEMM1 half h: streamed per row-tile (c1 = 16 regs at a time)
#pragma unroll
    for (int p = 0; p < 2; ++p){
      const int colh = p*256 + wid*32 + l31;
      const float bv = b1[h*512 + colh];
#pragma unroll 1
      for (int mt = 0; mt < 4; ++mt){
        f32x16 c1 = zero16();
#pragma unroll
        for (int ks = 0; ks < 2; ++ks){
          bf16x8 bw = ld16(w1opt + (((size_t)((h*16 + p*8 + wid)*2 + ks))*64 + l)*8);
          bf16x8 aw = ld16(l1p + (mt*32 + l31)*L1S + ks*32 + lh*16);
          c1 = mfma32(aw, bw, c1);
        }
#pragma unroll
        for (int r = 0; r < 16; ++r){
          const int row = mt*32 + (r & 3) + 8*(r >> 2) + 4*lh;
          *(unsigned short*)(h1 + row*H1S + colh*2) = f2bf(fmaxf(c1[r] + bv, 0.f));
        }
      }
    }
    __syncthreads();

    // ---- GEMM2 half h: 32 ks, rolled MM4 pipeline (forced unroll(1))
    {
      const char* pb0 = wB + h*32768;     // tile0; bumped +2048/iter
      const char* pb1 = pb0 + 65536;      // tile1
      int ao = 0;                         // A byte offset for ks=2t, bumped +64/iter

      bf16x8 A0e, A1e, A2e, A3e, A0o, A1o, A2o, A3o;
      bf16x8 Be0, Be1, Bo0, Bo1;

      // prologue: B ks0, A rows @ ks0, A rows01 @ ks1
      Be0 = ld16(pb0);           Be1 = ld16(pb1);
      A0e = ld16(h1 + a0o);      A1e = ld16(h1 + a1o);
      A2e = ld16(h1 + a2o);      A3e = ld16(h1 + a3o);
      A0o = ld16(h1 + a0o + 32); A1o = ld16(h1 + a1o + 32);

#pragma unroll 1
      for (int t = 0; t < 15; ++t){       // rolled — live set ~190 regs
        A2o = ld16(h1 + a2o + ao + 32);  A3o = ld16(h1 + a3o + ao + 32);   // A rows23 ks+1
        Bo0 = ld16(pb0 + 1024);          Bo1 = ld16(pb1 + 1024);          // B ks+1
        MM4R01(A0e, A1e, Be0, Be1);                                       // ks rows 0-63
        A0e = ld16(h1 + a0o + ao + 64);  A1e = ld16(h1 + a1o + ao + 64);  // A rows01 ks+2
        MM4R23(A2e, A3e, Be0, Be1);                                       // ks rows 64-127
        A2e = ld16(h1 + a2o + ao + 64);  A3e = ld16(h1 + a3o + ao + 64);  // A rows23 ks+2
        Be0 = ld16(pb0 + 2048);          Be1 = ld16(pb1 + 2048);          // B ks+2
        MM4R01(A0o, A1o, Bo0, Bo1);                                       // ks+1 rows 0-63
        A0o = ld16(h1 + a0o + ao + 96);  A1o = ld16(h1 + a1o + ao + 96);  // A rows01 ks+3
        MM4R23(A2o, A3o, Bo0, Bo1);                                       // ks+1 rows 64-127
        pb0 += 2048; pb1 += 2048; ao += 64;
      }
      // epilogue: ks 30,31 (Ae*/Be = ks30; A0o/A1o = ks31 from t=14; ao = 960)
      A2o = ld16(h1 + a2o + ao + 32);  A3o = ld16(h1 + a3o + ao + 32);    // A rows23 ks31
      Bo0 = ld16(pb0 + 1024);          Bo1 = ld16(pb1 + 1024);            // B ks31
      MM4R01(A0e, A1e, Be0, Be1);
      MM4R23(A2e, A3e, Be0, Be1);
      MM4R01(A0o, A1o, Bo0, Bo1);
      MM4R23(A2o, A3o, Bo0, Bo1);
    }
    __syncthreads();                      // done reading h1; next half overwrites
  }
#undef MM4R01
#undef MM4R23

  // ---- epilogue: h2 = relu(acc + b2); per-wave partial logits over its 64 cols;
  //      lane-reduce over l31; stage sp[wid][128][3] (overlays dead l1p/h1);
  //      cross-wave sum -> pws[bn].  (R12-verified logic.)
  float* sp = (float*)smem;
  {
    float b2v[2], w30[2], w31[2], w32[2];
#pragma unroll
    for (int nt = 0; nt < 2; ++nt){
      const int colg = bn*512 + wid*64 + nt*32 + l31;
      b2v[nt] = b2[colg];
      w30[nt] = W3[0*NEUR + colg];
      w31[nt] = W3[1*NEUR + colg];
      w32[nt] = W3[2*NEUR + colg];
    }
#pragma unroll
    for (int mt = 0; mt < 4; ++mt){
      float p0[16], p1[16], p2[16];
#pragma unroll
      for (int r = 0; r < 16; ++r){ p0[r] = 0.f; p1[r] = 0.f; p2[r] = 0.f; }
#pragma unroll
      for (int nt = 0; nt < 2; ++nt)
#pragma unroll
        for (int r = 0; r < 16; ++r){
          const float hv = fmaxf(acc[mt][nt][r] + b2v[nt], 0.f);
          p0[r] += hv * w30[nt];
          p1[r] += hv * w31[nt];
          p2[r] += hv * w32[nt];
        }
#pragma unroll
      for (int off = 1; off < 32; off <<= 1)
#pragma unroll
        for (int r = 0; r < 16; ++r){
          p0[r] += __shfl_xor(p0[r], off, 64);
          p1[r] += __shfl_xor(p1[r], off, 64);
          p2[r] += __shfl_xor(p2[r], off, 64);
        }
      if (l31 == 0){
#pragma unroll
        for (int r = 0; r < 16; ++r){
          const int row = mt*32 + (r & 3) + 8*(r >> 2) + 4*lh;
          float* d = sp + ((size_t)wid*BM + row)*3;
          d[0] = p0[r]; d[1] = p1[r]; d[2] = p2[r];
        }
      }
    }
  }
  __syncthreads();

  for (int t2 = tid; t2 < BM*3; t2 += THREADS){
    const int row = t2 / 3, j = t2 - row*3;
    float v = 0.f;
#pragma unroll
    for (int w = 0; w < 8; ++w) v += sp[((size_t)w*BM + row)*3 + j];
    pws[((size_t)bn*batch + rbase + row)*3 + j] = v;
  }
}

// ---------- fallback (ws too small): round-8 kernel, direct W2 reads ----------
__global__ __launch_bounds__(THREADS, 2) void mlp_kernel_old(
    const float* __restrict__ x,
    const float* __restrict__ Wx, const float* __restrict__ bxp,
    const float* __restrict__ Wu, const float* __restrict__ bup,
    const float* __restrict__ W1, const float* __restrict__ b1,
    const float* __restrict__ W2f, const float* __restrict__ b2,
    const float* __restrict__ W3, const float* __restrict__ b3,
    float* __restrict__ out)
{
  extern __shared__ char smem[];
  unsigned short* l1p = (unsigned short*)smem;
  char* h1 = smem + 5120;   // 64 x 2064
  const int tid = threadIdx.x, l = tid & 63, wid = tid >> 6;
  const int l31 = l & 31, lh = l >> 5;
  const long rbase = (long)blockIdx.x * 64;

  float* xs = (float*)h1;
  for (int i = tid; i < 64*25; i += THREADS) xs[i] = x[rbase*25 + i];
  __syncthreads();
  if (tid < 64){
    const float* xr = xs + tid*25;
    float l1v[10];
#pragma unroll
    for (int g = 0; g < 3; ++g)
#pragma unroll
      for (int o = 0; o < 2; ++o){
        float s = bxp[o];
#pragma unroll
        for (int i = 0; i < 5; ++i) s += xr[g + 3*i] * Wx[o*5 + i];
        l1v[g*2 + o] = fmaxf(s, 0.f);
      }
#pragma unroll
    for (int g = 0; g < 2; ++g)
#pragma unroll
      for (int o = 0; o < 2; ++o){
        float s = bup[o];
#pragma unroll
        for (int i = 0; i < 5; ++i) s += xr[15 + g + 2*i] * Wu[o*5 + i];
        l1v[6 + g*2 + o] = fmaxf(s, 0.f);
      }
    unsigned short* dst = l1p + tid*40;
#pragma unroll
    for (int i = 0; i < 10; ++i) dst[i] = f2bf(l1v[i]);
#pragma unroll
    for (int i = 10; i < 32; ++i) dst[i] = 0;
  }
  __syncthreads();

  f32x16 c[2][4];
#pragma unroll
  for (int mt = 0; mt < 2; ++mt)
#pragma unroll
    for (int nt = 0; nt < 4; ++nt) c[mt][nt] = zero16();
#pragma unroll
  for (int ks = 0; ks < 2; ++ks){
    bf16x8 a0 = ld16(smem + l31*80 + ks*32 + lh*16);
    bf16x8 a1 = ld16(smem + (32 + l31)*80 + ks*32 + lh*16);
#pragma unroll
    for (int nt = 0; nt < 4; ++nt){
      const int col = wid*128 + nt*32 + l31;
      s16x8 raw;
#pragma unroll
      for (int j = 0; j < 8; ++j){
        const int k = ks*16 + lh*8 + j;
        raw[j] = (k < 10) ? (short)f2bf(W1[col*10 + k]) : (short)0;
      }
      bf16x8 b = __builtin_bit_cast(bf16x8, raw);
      c[0][nt] = mfma32(a0, b, c[0][nt]);
      c[1][nt] = mfma32(a1, b, c[1][nt]);
    }
  }
#pragma unroll
  for (int nt = 0; nt < 4; ++nt){
    const int col = wid*128 + nt*32 + l31;
    const float bv = b1[col];
#pragma unroll
    for (int mt = 0; mt < 2; ++mt)
#pragma unroll
      for (int r = 0; r < 16; ++r){
        const int row = mt*32 + (r & 3) + 8*(r >> 2) + 4*lh;
        *reinterpret_cast<unsigned short*>(h1 + row*2064 + col*2) =
            f2bf(fmaxf(c[mt][nt][r] + bv, 0.f));
      }
  }
  __syncthreads();

  f32x16 acc[2][4];
#pragma unroll
  for (int mt = 0; mt < 2; ++mt)
#pragma unroll
    for (int nt = 0; nt < 4; ++nt) acc[mt][nt] = zero16();
  const int aA0 = l31*2064 + lh*16;
  for (int ks = 0; ks < 64; ++ks){
    bf16x8 A0 = ld16(h1 + aA0 + ks*32);
    bf16x8 A1 = ld16(h1 + aA0 + 32*2064 + ks*32);
#pragma unroll
    for (int nt = 0; nt < 4; ++nt){
      const int col = wid*128 + nt*32 + l31;
      const float* p = W2f + (size_t)col*NEUR + ks*16 + lh*8;
      s16x8 raw;
#pragma unroll
      for (int j = 0; j < 8; ++j) raw[j] = (short)f2bf(p[j]);
      bf16x8 B = __builtin_bit_cast(bf16x8, raw);
      acc[0][nt] = mfma32(A0, B, acc[0][nt]);
      acc[1][nt] = mfma32(A1, B, acc[1][nt]);
    }
  }
  __syncthreads();
#pragma unroll
  for (int nt = 0; nt < 4; ++nt){
    const int col = wid*128 + nt*32 + l31;
    const float bv = b2[col];
#pragma unroll
    for (int mt = 0; mt < 2; ++mt)
#pragma unroll
      for (int r = 0; r < 16; ++r){
        const int row = mt*32 + (r & 3) + 8*(r >> 2) + 4*lh;
        *reinterpret_cast<unsigned short*>(h1 + row*2064 + col*2) =
            f2bf(fmaxf(acc[mt][nt][r] + bv, 0.f));
      }
  }
  __syncthreads();
  float s[8][3];
#pragma unroll
  for (int rr = 0; rr < 8; ++rr)
#pragma unroll
    for (int j = 0; j < 3; ++j) s[rr][j] = 0.f;
#pragma unroll
  for (int h = 0; h < 2; ++h){
    const int k0 = h*512 + l*8;
    float w3v[3][8];
#pragma unroll
    for (int j = 0; j < 3; ++j)
#pragma unroll
      for (int i = 0; i < 8; ++i) w3v[j][i] = W3[j*NEUR + k0 + i];
#pragma unroll
    for (int rr = 0; rr < 8; ++rr){
      const int row = wid*8 + rr;
      s16x8 raw = *reinterpret_cast<const s16x8*>(h1 + row*2064 + k0*2);
#pragma unroll
      for (int i = 0; i < 8; ++i){
        const float hv = bf2f((unsigned short)raw[i]);
        s[rr][0] += hv * w3v[0][i];
        s[rr][1] += hv * w3v[1][i];
        s[rr][2] += hv * w3v[2][i];
      }
    }
  }
#pragma unroll
  for (int off = 1; off < 64; off <<= 1)
#pragma unroll
    for (int rr = 0; rr < 8; ++rr)
#pragma unroll
      for (int j = 0; j < 3; ++j) s[rr][j] += __shfl_xor(s[rr][j], off, 64);
  if (l == 0){
#pragma unroll
    for (int rr = 0; rr < 8; ++rr){
      const int row = wid*8 + rr;
#pragma unroll
      for (int j = 0; j < 3; ++j)
        out[(rbase + row)*3 + j] = 1.f / (1.f + __expf(-(s[rr][j] + b3[j])));
    }
  }
}

extern "C" void kernel_launch(void* const* d_in, const int* in_sizes, int n_in,
                              void* d_out, int out_size, void* d_ws, size_t ws_size,
                              hipStream_t stream){
  const float* x  = (const float*)d_in[0];
  const float* Wx = (const float*)d_in[1];
  const float* bx = (const float*)d_in[2];
  const float* Wu = (const float*)d_in[3];
  const float* bu = (const float*)d_in[4];
  const float* W1 = (const float*)d_in[5];
  const float* b1 = (const float*)d_in[6];
  const float* W2 = (const float*)d_in[7];
  const float* b2 = (const float*)d_in[8];
  const float* W3 = (const float*)d_in[9];
  const float* b3 = (const float*)d_in[10];
  float* out = (float*)d_out;

  const int batch = in_sizes[0] / 25;
  const size_t w2_bytes  = (size_t)NEUR*NEUR*2;          // 2 MB
  const size_t w1_bytes  = (size_t)4096*8*2;             // 64 KB
  const size_t pws_bytes = (size_t)batch*3*2*4;          // 3.1 MB
  const size_t ws_need   = w2_bytes + w1_bytes + pws_bytes;

  if (ws_size >= ws_need && (batch % BM) == 0){
    unsigned short* w2opt = (unsigned short*)d_ws;
    unsigned short* w1opt = (unsigned short*)((char*)d_ws + w2_bytes);
    float* pws            = (float*)((char*)d_ws + w2_bytes + w1_bytes);

    prep_kernel<<<512, 256, 0, stream>>>(W1, W2, w2opt, w1opt);

    const int smem = BM*L1S + BM*H1S;   // 10240 + 133120 = 143360 B
    hipFuncSetAttribute(reinterpret_cast<const void*>(mlp_kernel),
                        hipFuncAttributeMaxDynamicSharedMemorySize, smem);
    const int nblocks = (batch / BM) * 2;
    mlp_kernel<<<nblocks, THREADS, smem, stream>>>(
        x, Wx, bx, Wu, bu, b1, b2, W3, w2opt, w1opt, pws, batch);

    finish_kernel<<<(batch*3 + 255)/256, 256, 0, stream>>>(pws, b3, out, batch);
  } else {
    const int smem = 5120 + 64*2064;
    hipFuncSetAttribute(reinterpret_cast<const void*>(mlp_kernel_old),
                        hipFuncAttributeMaxDynamicSharedMemorySize, smem);
    mlp_kernel_old<<<batch/64, THREADS, smem, stream>>>(
        x, Wx, bx, Wu, bu, W1, b1, W2, b2, W3, b3, out);
  }
}

// Round 16
// 418.670 us; speedup vs baseline: 1.0899x; 1.0239x over previous
//
#include <hip/hip_runtime.h>
#include <stdint.h>

#define NEUR 1024
#define BM 64             // rows per block
#define THREADS 256       // 4 waves; 3 blocks/CU -> 12 waves/CU
#define H1S 528           // h1 quarter row stride bytes (256 bf16 + 16B pad)
#define L1S 80            // l1p row stride bytes

typedef short  s16x8  __attribute__((ext_vector_type(8)));
typedef __bf16 bf16x8 __attribute__((ext_vector_type(8)));
typedef float  f32x16 __attribute__((ext_vector_type(16)));

__device__ __forceinline__ unsigned short f2bf(float f){
  unsigned u = __builtin_bit_cast(unsigned, f);
  u += 0x7FFFu + ((u >> 16) & 1u);          // round-to-nearest-even
  return (unsigned short)(u >> 16);
}
__device__ __forceinline__ float bf2f(unsigned short h){
  unsigned u = ((unsigned)h) << 16;
  return __builtin_bit_cast(float, u);
}
__device__ __forceinline__ f32x16 mfma32(bf16x8 a, bf16x8 b, f32x16 c){
  return __builtin_amdgcn_mfma_f32_32x32x16_bf16(a, b, c, 0, 0, 0);
}
__device__ __forceinline__ f32x16 zero16(){
  f32x16 v;
#pragma unroll
  for (int r = 0; r < 16; ++r) v[r] = 0.f;
  return v;
}
__device__ __forceinline__ bf16x8 ld16(const void* p){
  return __builtin_bit_cast(bf16x8, *reinterpret_cast<const s16x8*>(p));
}

// Pre-swizzle weights into MFMA-fragment order (coalesced GEMM loads).
// w2opt[((nt*64 + ks)*64 + l)*8 + j] = bf16(W2[nt*32 + (l&31)][ks*16 + (l>>5)*8 + j])
// w1opt[((nt*2  + ks)*64 + l)*8 + j] = bf16(W1 padded to K=32, same fragment map)
__global__ void prep_kernel(const float* __restrict__ W1, const float* __restrict__ W2,
                            unsigned short* __restrict__ w2opt, unsigned short* __restrict__ w1opt){
  const int nchunks = NEUR * 128;
  const int total = nchunks + 4096;
  for (int i = blockIdx.x*blockDim.x + threadIdx.x; i < total; i += gridDim.x*blockDim.x){
    if (i < nchunks){
      const int col = i >> 7, c8 = i & 127;
      const float* src = W2 + (size_t)col*NEUR + c8*8;
      const int ks = c8 >> 1, lf = c8 & 1, lane = lf*32 + (col & 31), nt = col >> 5;
      unsigned short* dst = w2opt + (((size_t)(nt*64 + ks)*64 + lane) * 8);
#pragma unroll
      for (int j = 0; j < 8; ++j) dst[j] = f2bf(src[j]);
    } else {
      const int o = i - nchunks;
      const int nt = o >> 7, ks = (o >> 6) & 1, lane = o & 63;
      const int col = nt*32 + (lane & 31);
      unsigned short* dst = w1opt + (size_t)o * 8;
#pragma unroll
      for (int j = 0; j < 8; ++j){
        const int k = ks*16 + (lane >> 5)*8 + j;
        dst[j] = (k < 10) ? f2bf(W1[col*10 + k]) : (unsigned short)0;
      }
    }
  }
}

// finish: out = sigmoid(sum of 4 bf16 partial slabs + b3)
__global__ void finish_kernel(const unsigned short* __restrict__ pws, const float* __restrict__ b3,
                              float* __restrict__ out, int batch){
  const int total = batch * 3;
  for (int i = blockIdx.x*blockDim.x + threadIdx.x; i < total; i += gridDim.x*blockDim.x){
    const int j = i - (i/3)*3;
    float v = b3[j];
#pragma unroll
    for (int s = 0; s < 4; ++s) v += bf2f(pws[(size_t)s*total + i]);
    out[i] = 1.f / (1.f + __expf(-v));
  }
}

// Main fused kernel: 64 rows x 256 W2-cols per block, K quartered (h1 = 256 neurons
// at a time). 4 waves/block, 3 blocks/CU (12 waves/CU = 3/SIMD) — barrier drains and
// load latency of one block overlap with the other two blocks' MFMA.
__global__ __launch_bounds__(THREADS, 3) void mlp_kernel(
    const float* __restrict__ x,
    const float* __restrict__ Wx, const float* __restrict__ bxp,
    const float* __restrict__ Wu, const float* __restrict__ bup,
    const float* __restrict__ b1, const float* __restrict__ b2,
    const float* __restrict__ W3,
    const unsigned short* __restrict__ w2opt, const unsigned short* __restrict__ w1opt,
    unsigned short* __restrict__ pws, int batch)
{
  extern __shared__ char smem[];
  char* l1p = smem;                       // [64][L1S] 5120 B (overlaid by sp in epilogue)
  char* h1  = smem + BM*L1S;              // [64][H1S] 33792 B  (total 38912)

  const int tid = threadIdx.x;
  const int l   = tid & 63;
  const int wid = tid >> 6;               // 4 waves; wave owns cols wid*64..+64 of block's 256
  const int l31 = l & 31;
  const int lh  = l >> 5;
  const int bm  = blockIdx.x >> 2;
  const int bn  = blockIdx.x & 3;
  const long rbase = (long)bm * BM;

  // ---- 1. stage x tile (64*25 f32) into h1 region
  float* xs = (float*)h1;
  for (int i = tid; i < BM*25; i += THREADS) xs[i] = x[rbase*25 + i];
  __syncthreads();

  // ---- 2. l1 features (f32 exact), bf16-pad to K=32
  if (tid < BM){
    const float* xr = xs + tid*25;
    float l1v[10];
#pragma unroll
    for (int g = 0; g < 3; ++g)
#pragma unroll
      for (int o = 0; o < 2; ++o){
        float s = bxp[o];
#pragma unroll
        for (int i = 0; i < 5; ++i) s += xr[g + 3*i] * Wx[o*5 + i];
        l1v[g*2 + o] = fmaxf(s, 0.f);
      }
#pragma unroll
    for (int g = 0; g < 2; ++g)
#pragma unroll
      for (int o = 0; o < 2; ++o){
        float s = bup[o];
#pragma unroll
        for (int i = 0; i < 5; ++i) s += xr[15 + g + 2*i] * Wu[o*5 + i];
        l1v[6 + g*2 + o] = fmaxf(s, 0.f);
      }
    unsigned short* dst = (unsigned short*)(l1p + tid*L1S);
#pragma unroll
    for (int i = 0; i < 10; ++i) dst[i] = f2bf(l1v[i]);
#pragma unroll
    for (int i = 10; i < 32; ++i) dst[i] = 0;
  }
  __syncthreads();

  // ---- persistent GEMM2 accumulators: wave tile 64 rows x 64 cols
  f32x16 acc[2][2];
#pragma unroll
  for (int mt = 0; mt < 2; ++mt)
#pragma unroll
    for (int nt = 0; nt < 2; ++nt) acc[mt][nt] = zero16();

  const int a0o = (0*32 + l31)*H1S + lh*16;     // A frag row bases in h1
  const int a1o = (1*32 + l31)*H1S + lh*16;

  // wave's two B n-tiles (global tiles bn*8 + wid*2 + {0,1}); tile stride 65536 B
  const char* const wB = (const char*)w2opt + ((size_t)(bn*8 + wid*2))*65536 + (size_t)l*16;

#define MM4(A0_,A1_,B0_,B1_) do{ __builtin_amdgcn_s_setprio(1);                 \
    acc[0][0]=mfma32(A0_,B0_,acc[0][0]); acc[0][1]=mfma32(A0_,B1_,acc[0][1]);   \
    acc[1][0]=mfma32(A1_,B0_,acc[1][0]); acc[1][1]=mfma32(A1_,B1_,acc[1][1]);   \
    __builtin_amdgcn_s_setprio(0); }while(0)

  for (int q = 0; q < 4; ++q){
    // ---- GEMM1 quarter q: h1[64][256] = relu(l1 @ W1[q*256..+256]^T + b1), streamed
#pragma unroll
    for (int p = 0; p < 2; ++p){
      const int colq = wid*64 + p*32 + l31;       // col within quarter
      const int ntg  = q*8 + wid*2 + p;           // global W1 fragment tile
      const float bv = b1[q*256 + colq];
#pragma unroll
      for (int mt = 0; mt < 2; ++mt){
        f32x16 c1 = zero16();
#pragma unroll
        for (int ks = 0; ks < 2; ++ks){
          bf16x8 bw = ld16(w1opt + (((size_t)ntg*2 + ks)*64 + l)*8);
          bf16x8 aw = ld16(l1p + (mt*32 + l31)*L1S + ks*32 + lh*16);
          c1 = mfma32(aw, bw, c1);
        }
#pragma unroll
        for (int r = 0; r < 16; ++r){
          const int row = mt*32 + (r & 3) + 8*(r >> 2) + 4*lh;
          *(unsigned short*)(h1 + row*H1S + colq*2) = f2bf(fmaxf(c1[r] + bv, 0.f));
        }
      }
    }
    __syncthreads();

    // ---- GEMM2 quarter q: 16 ks, distance-2 ping-pong (R8 schedule, 2A x 2B)
    {
      const char* pb0 = wB + q*16384;             // ks stride 1024 B within tile
      const char* pb1 = pb0 + 65536;
      int ao = 0;

      bf16x8 Ae0, Ae1, Ao0, Ao1, Be0, Be1, Bo0, Bo1;
      Be0 = ld16(pb0);            Be1 = ld16(pb1);
      Ae0 = ld16(h1 + a0o);       Ae1 = ld16(h1 + a1o);
      Ao0 = ld16(h1 + a0o + 32);  Ao1 = ld16(h1 + a1o + 32);

      for (int t = 0; t < 7; ++t){                // ks pairs 0..13
        Bo0 = ld16(pb0 + 1024);          Bo1 = ld16(pb1 + 1024);          // B ks+1
        MM4(Ae0, Ae1, Be0, Be1);                                          // ks
        Ae0 = ld16(h1 + a0o + ao + 64);  Ae1 = ld16(h1 + a1o + ao + 64);  // A ks+2
        Be0 = ld16(pb0 + 2048);          Be1 = ld16(pb1 + 2048);          // B ks+2
        MM4(Ao0, Ao1, Bo0, Bo1);                                          // ks+1
        Ao0 = ld16(h1 + a0o + ao + 96);  Ao1 = ld16(h1 + a1o + ao + 96);  // A ks+3
        pb0 += 2048; pb1 += 2048; ao += 64;
      }
      // tail: ks 14,15  (Ae/Be = ks14; Ao = ks15 from t=6)
      Bo0 = ld16(pb0 + 1024);  Bo1 = ld16(pb1 + 1024);
      MM4(Ae0, Ae1, Be0, Be1);
      MM4(Ao0, Ao1, Bo0, Bo1);
    }
    __syncthreads();                              // next quarter overwrites h1
  }
#undef MM4

  // ---- epilogue: h2 = relu(acc + b2); per-wave partial logits over its 64 cols;
  //      lane-reduce over l31; stage sp[wid][64][3] (overlays dead l1p);
  //      cross-wave sum -> bf16 pws slab bn.
  float* sp = (float*)smem;
  {
    float b2v[2], w30[2], w31[2], w32[2];
#pragma unroll
    for (int nt = 0; nt < 2; ++nt){
      const int colg = bn*256 + wid*64 + nt*32 + l31;
      b2v[nt] = b2[colg];
      w30[nt] = W3[0*NEUR + colg];
      w31[nt] = W3[1*NEUR + colg];
      w32[nt] = W3[2*NEUR + colg];
    }
#pragma unroll
    for (int mt = 0; mt < 2; ++mt){
      float p0[16], p1[16], p2[16];
#pragma unroll
      for (int r = 0; r < 16; ++r){ p0[r] = 0.f; p1[r] = 0.f; p2[r] = 0.f; }
#pragma unroll
      for (int nt = 0; nt < 2; ++nt)
#pragma unroll
        for (int r = 0; r < 16; ++r){
          const float hv = fmaxf(acc[mt][nt][r] + b2v[nt], 0.f);
          p0[r] += hv * w30[nt];
          p1[r] += hv * w31[nt];
          p2[r] += hv * w32[nt];
        }
#pragma unroll
      for (int off = 1; off < 32; off <<= 1)
#pragma unroll
        for (int r = 0; r < 16; ++r){
          p0[r] += __shfl_xor(p0[r], off, 64);
          p1[r] += __shfl_xor(p1[r], off, 64);
          p2[r] += __shfl_xor(p2[r], off, 64);
        }
      if (l31 == 0){
#pragma unroll
        for (int r = 0; r < 16; ++r){
          const int row = mt*32 + (r & 3) + 8*(r >> 2) + 4*lh;
          float* d = sp + ((size_t)wid*BM + row)*3;
          d[0] = p0[r]; d[1] = p1[r]; d[2] = p2[r];
        }
      }
    }
  }
  __syncthreads();

  for (int t2 = tid; t2 < BM*3; t2 += THREADS){
    const int row = t2 / 3, j = t2 - row*3;
    float v = 0.f;
#pragma unroll
    for (int w = 0; w < 4; ++w) v += sp[((size_t)w*BM + row)*3 + j];
    pws[(size_t)bn*batch*3 + (rbase + row)*3 + j] = f2bf(v);
  }
}

// ---------- fallback (ws too small): R8-style kernel, direct W2 reads ----------
__global__ __launch_bounds__(512, 2) void mlp_kernel_old(
    const float* __restrict__ x,
    const float* __restrict__ Wx, const float* __restrict__ bxp,
    const float* __restrict__ Wu, const float* __restrict__ bup,
    const float* __restrict__ W1, const float* __restrict__ b1,
    const float* __restrict__ W2f, const float* __restrict__ b2,
    const float* __restrict__ W3, const float* __restrict__ b3,
    float* __restrict__ out)
{
  extern __shared__ char smem[];
  unsigned short* l1p = (unsigned short*)smem;
  char* h1 = smem + 5120;   // 64 x 2064
  const int tid = threadIdx.x, l = tid & 63, wid = tid >> 6;
  const int l31 = l & 31, lh = l >> 5;
  const long rbase = (long)blockIdx.x * 64;

  float* xs = (float*)h1;
  for (int i = tid; i < 64*25; i += 512) xs[i] = x[rbase*25 + i];
  __syncthreads();
  if (tid < 64){
    const float* xr = xs + tid*25;
    float l1v[10];
#pragma unroll
    for (int g = 0; g < 3; ++g)
#pragma unroll
      for (int o = 0; o < 2; ++o){
        float s = bxp[o];
#pragma unroll
        for (int i = 0; i < 5; ++i) s += xr[g + 3*i] * Wx[o*5 + i];
        l1v[g*2 + o] = fmaxf(s, 0.f);
      }
#pragma unroll
    for (int g = 0; g < 2; ++g)
#pragma unroll
      for (int o = 0; o < 2; ++o){
        float s = bup[o];
#pragma unroll
        for (int i = 0; i < 5; ++i) s += xr[15 + g + 2*i] * Wu[o*5 + i];
        l1v[6 + g*2 + o] = fmaxf(s, 0.f);
      }
    unsigned short* dst = l1p + tid*40;
#pragma unroll
    for (int i = 0; i < 10; ++i) dst[i] = f2bf(l1v[i]);
#pragma unroll
    for (int i = 10; i < 32; ++i) dst[i] = 0;
  }
  __syncthreads();

  f32x16 c[2][4];
#pragma unroll
  for (int mt = 0; mt < 2; ++mt)
#pragma unroll
    for (int nt = 0; nt < 4; ++nt) c[mt][nt] = zero16();
#pragma unroll
  for (int ks = 0; ks < 2; ++ks){
    bf16x8 a0 = ld16(smem + l31*80 + ks*32 + lh*16);
    bf16x8 a1 = ld16(smem + (32 + l31)*80 + ks*32 + lh*16);
#pragma unroll
    for (int nt = 0; nt < 4; ++nt){
      const int col = wid*128 + nt*32 + l31;
      s16x8 raw;
#pragma unroll
      for (int j = 0; j < 8; ++j){
        const int k = ks*16 + lh*8 + j;
        raw[j] = (k < 10) ? (short)f2bf(W1[col*10 + k]) : (short)0;
      }
      bf16x8 b = __builtin_bit_cast(bf16x8, raw);
      c[0][nt] = mfma32(a0, b, c[0][nt]);
      c[1][nt] = mfma32(a1, b, c[1][nt]);
    }
  }
#pragma unroll
  for (int nt = 0; nt < 4; ++nt){
    const int col = wid*128 + nt*32 + l31;
    const float bv = b1[col];
#pragma unroll
    for (int mt = 0; mt < 2; ++mt)
#pragma unroll
      for (int r = 0; r < 16; ++r){
        const int row = mt*32 + (r & 3) + 8*(r >> 2) + 4*lh;
        *reinterpret_cast<unsigned short*>(h1 + row*2064 + col*2) =
            f2bf(fmaxf(c[mt][nt][r] + bv, 0.f));
      }
  }
  __syncthreads();

  f32x16 acc[2][4];
#pragma unroll
  for (int mt = 0; mt < 2; ++mt)
#pragma unroll
    for (int nt = 0; nt < 4; ++nt) acc[mt][nt] = zero16();
  const int aA0 = l31*2064 + lh*16;
  for (int ks = 0; ks < 64; ++ks){
    bf16x8 A0 = ld16(h1 + aA0 + ks*32);
    bf16x8 A1 = ld16(h1 + aA0 + 32*2064 + ks*32);
#pragma unroll
    for (int nt = 0; nt < 4; ++nt){
      const int col = wid*128 + nt*32 + l31;
      const float* p = W2f + (size_t)col*NEUR + ks*16 + lh*8;
      s16x8 raw;
#pragma unroll
      for (int j = 0; j < 8; ++j) raw[j] = (short)f2bf(p[j]);
      bf16x8 B = __builtin_bit_cast(bf16x8, raw);
      acc[0][nt] = mfma32(A0, B, acc[0][nt]);
      acc[1][nt] = mfma32(A1, B, acc[1][nt]);
    }
  }
  __syncthreads();
#pragma unroll
  for (int nt = 0; nt < 4; ++nt){
    const int col = wid*128 + nt*32 + l31;
    const float bv = b2[col];
#pragma unroll
    for (int mt = 0; mt < 2; ++mt)
#pragma unroll
      for (int r = 0; r < 16; ++r){
        const int row = mt*32 + (r & 3) + 8*(r >> 2) + 4*lh;
        *reinterpret_cast<unsigned short*>(h1 + row*2064 + col*2) =
            f2bf(fmaxf(acc[mt][nt][r] + bv, 0.f));
      }
  }
  __syncthreads();
  float s[8][3];
#pragma unroll
  for (int rr = 0; rr < 8; ++rr)
#pragma unroll
    for (int j = 0; j < 3; ++j) s[rr][j] = 0.f;
#pragma unroll
  for (int h = 0; h < 2; ++h){
    const int k0 = h*512 + l*8;
    float w3v[3][8];
#pragma unroll
    for (int j = 0; j < 3; ++j)
#pragma unroll
      for (int i = 0; i < 8; ++i) w3v[j][i] = W3[j*NEUR + k0 + i];
#pragma unroll
    for (int rr = 0; rr < 8; ++rr){
      const int row = wid*8 + rr;
      s16x8 raw = *reinterpret_cast<const s16x8*>(h1 + row*2064 + k0*2);
#pragma unroll
      for (int i = 0; i < 8; ++i){
        const float hv = bf2f((unsigned short)raw[i]);
        s[rr][0] += hv * w3v[0][i];
        s[rr][1] += hv * w3v[1][i];
        s[rr][2] += hv * w3v[2][i];
      }
    }
  }
#pragma unroll
  for (int off = 1; off < 64; off <<= 1)
#pragma unroll
    for (int rr = 0; rr < 8; ++rr)
#pragma unroll
      for (int j = 0; j < 3; ++j) s[rr][j] += __shfl_xor(s[rr][j], off, 64);
  if (l == 0){
#pragma unroll
    for (int rr = 0; rr < 8; ++rr){
      const int row = wid*8 + rr;
#pragma unroll
      for (int j = 0; j < 3; ++j)
        out[(rbase + row)*3 + j] = 1.f / (1.f + __expf(-(s[rr][j] + b3[j])));
    }
  }
}

extern "C" void kernel_launch(void* const* d_in, const int* in_sizes, int n_in,
                              void* d_out, int out_size, void* d_ws, size_t ws_size,
                              hipStream_t stream){
  const float* x  = (const float*)d_in[0];
  const float* Wx = (const float*)d_in[1];
  const float* bx = (const float*)d_in[2];
  const float* Wu = (const float*)d_in[3];
  const float* bu = (const float*)d_in[4];
  const float* W1 = (const float*)d_in[5];
  const float* b1 = (const float*)d_in[6];
  const float* W2 = (const float*)d_in[7];
  const float* b2 = (const float*)d_in[8];
  const float* W3 = (const float*)d_in[9];
  const float* b3 = (const float*)d_in[10];
  float* out = (float*)d_out;

  const int batch = in_sizes[0] / 25;
  const size_t w2_bytes  = (size_t)NEUR*NEUR*2;          // 2 MB
  const size_t w1_bytes  = (size_t)4096*8*2;             // 64 KB
  const size_t pws_bytes = (size_t)batch*3*4*2;          // 4 slabs x bf16 = 3.1 MB
  const size_t ws_need   = w2_bytes + w1_bytes + pws_bytes;   // 5.3 MB (known-good size)

  if (ws_size >= ws_need && (batch % BM) == 0){
    unsigned short* w2opt = (unsigned short*)d_ws;
    unsigned short* w1opt = (unsigned short*)((char*)d_ws + w2_bytes);
    unsigned short* pws   = (unsigned short*)((char*)d_ws + w2_bytes + w1_bytes);

    prep_kernel<<<512, 256, 0, stream>>>(W1, W2, w2opt, w1opt);

    const int smem = BM*L1S + BM*H1S;   // 5120 + 33792 = 38912 B (3 blocks/CU)
    hipFuncSetAttribute(reinterpret_cast<const void*>(mlp_kernel),
                        hipFuncAttributeMaxDynamicSharedMemorySize, smem);
    const int nblocks = (batch / BM) * 4;
    mlp_kernel<<<nblocks, THREADS, smem, stream>>>(
        x, Wx, bx, Wu, bu, b1, b2, W3, w2opt, w1opt, pws, batch);

    finish_kernel<<<(batch*3 + 255)/256, 256, 0, stream>>>(pws, b3, out, batch);
  } else {
    const int smem = 5120 + 64*2064;
    hipFuncSetAttribute(reinterpret_cast<const void*>(mlp_kernel_old),
                        hipFuncAttributeMaxDynamicSharedMemorySize, smem);
    mlp_kernel_old<<<batch/64, 512, smem, stream>>>(
        x, Wx, bx, Wu, bu, W1, b1, W2, b2, W3, b3, out);
  }
}